// Round 10
// baseline (247.749 us; speedup 1.0000x reference)
//
#include <hip/hip_runtime.h>
#include <cstdint>

// Problem constants: B=2, L=2048, D=1024, H=16, HS=64
#define SEQ 2048
#define DMODEL 1024
#define NHEAD 16
#define HEADSZ 64

typedef __attribute__((ext_vector_type(4))) float f32x4;
typedef __attribute__((ext_vector_type(16))) float f32x16;
typedef __attribute__((ext_vector_type(8))) short short8;
typedef __attribute__((ext_vector_type(4))) unsigned short u16x4;
typedef __attribute__((ext_vector_type(4))) unsigned int u32x4;

#define AS1 __attribute__((address_space(1)))
#define AS3 __attribute__((address_space(3)))

__device__ __forceinline__ void gload_lds16(const void* g, void* l) {
  // async global->LDS, 16B per lane; LDS dest is wave-uniform base (+lane*16 by HW)
  __builtin_amdgcn_global_load_lds((const AS1 void*)g, (AS3 void*)l, 16, 0, 0);
}

__device__ __forceinline__ unsigned short f2bf(float f) {
  unsigned u = __float_as_uint(f);
  u += 0x7fffu + ((u >> 16) & 1u);   // RNE
  return (unsigned short)(u >> 16);
}

__device__ __forceinline__ unsigned pack2bf(float lo, float hi) {
  return (unsigned)f2bf(lo) | ((unsigned)f2bf(hi) << 16);
}

// ---------------------------------------------------------------------------
// Kernel 1: fp32 -> bf16 conversion of x and concat(Wq,Wk,Wv)
// ---------------------------------------------------------------------------
__global__ __launch_bounds__(256) void convert_kernel(
    const float* __restrict__ x, const float* __restrict__ wq,
    const float* __restrict__ wk, const float* __restrict__ wv,
    unsigned short* __restrict__ xb, unsigned short* __restrict__ wb) {
  const long i = ((long)blockIdx.x * 256 + threadIdx.x) * 4;
  const float* src;
  unsigned short* dst;
  if (i < (1L << 22)) {               // x: 4M elements
    src = x + i; dst = xb + i;
  } else {
    const long j = i - (1L << 22);    // wb: 3M elements (Wq|Wk|Wv rows)
    dst = wb + j;
    if (j < (1L << 20))        src = wq + j;
    else if (j < (2L << 20))   src = wk + (j - (1L << 20));
    else                       src = wv + (j - (2L << 20));
  }
  f32x4 v = *(const f32x4*)src;
  u16x4 o;
  o.x = f2bf(v.x); o.y = f2bf(v.y); o.z = f2bf(v.z); o.w = f2bf(v.w);
  *(u16x4*)dst = o;
}

// ---------------------------------------------------------------------------
// Kernel 2: QKV projection GEMM.  Round-9: double-buffered LDS, stage(ks+1)
// issued BEFORE compute(ks), ONE barrier per K-step (vmcnt drain overlaps
// MFMA instead of preceding it). LDS 64KB -> 2 blocks/CU.
// ---------------------------------------------------------------------------
__global__ __launch_bounds__(256) void qkv_gemm(
    const unsigned short* __restrict__ xb, const unsigned short* __restrict__ wb,
    const float* __restrict__ bq, const float* __restrict__ bk,
    const float* __restrict__ bv,
    unsigned short* __restrict__ qo, unsigned short* __restrict__ ko,
    unsigned short* __restrict__ vto) {
  __shared__ __attribute__((aligned(16))) unsigned short Sh[2][2][128 * 64]; // 64KB

  const int bid = blockIdx.x;                  // nwg = 32*24 = 768 (div by 8)
  const int swz = (bid & 7) * 96 + (bid >> 3); // XCD-contiguous chunks
  const int tm = swz / 24, tn = swz % 24;
  const int m0 = tm * 128, n0 = tn * 128;
  const int tsel = n0 >> 10;                   // block-uniform: 0=Q 1=K 2=V
  const int t = threadIdx.x;
  const int lane = t & 63, wid = t >> 6;
  const int wr = wid >> 1, wc = wid & 1;
  const int r16 = lane & 15, g4 = lane >> 4;

  f32x4 acc[4][4] = {};

  const unsigned short* ga0 = xb + (long)(m0 + (t >> 3)) * 1024 + (t & 7) * 8;
  const unsigned short* gb0 = wb + (long)(n0 + (t >> 3)) * 1024 + (t & 7) * 8;

  // stage K-step ks into buffer buf
  auto stage = [&](int ks, int buf) {
    const unsigned short* ga = ga0 + ks * 64;
    const unsigned short* gb = gb0 + ks * 64;
    char* lA = (char*)&Sh[buf][0][0] + wid * 1024;
    char* lB = (char*)&Sh[buf][1][0] + wid * 1024;
#pragma unroll
    for (int r = 0; r < 4; ++r) {
      gload_lds16(ga + r * 32 * 1024, lA + r * 4096);
      gload_lds16(gb + r * 32 * 1024, lB + r * 4096);
    }
  };

  stage(0, 0);
  __syncthreads();

  int cur = 0;
  for (int ks = 0; ks < 16; ++ks) {
    if (ks < 15) stage(ks + 1, cur ^ 1);   // loads fly under this step's MFMA
    const char* As = (const char*)&Sh[cur][0][0];
    const char* Bs = (const char*)&Sh[cur][1][0];
#pragma unroll
    for (int kk = 0; kk < 2; ++kk) {
      short8 af[4], bf[4];
#pragma unroll
      for (int mi = 0; mi < 4; ++mi)
        af[mi] = *(const short8*)(As +
                 (wr * 64 + mi * 16 + r16) * 128 + kk * 64 + g4 * 16);
#pragma unroll
      for (int ni = 0; ni < 4; ++ni)
        bf[ni] = *(const short8*)(Bs +
                 (wc * 64 + ni * 16 + r16) * 128 + kk * 64 + g4 * 16);
      if (tsel < 2) {
#pragma unroll
        for (int mi = 0; mi < 4; ++mi)
#pragma unroll
          for (int ni = 0; ni < 4; ++ni)
            acc[mi][ni] = __builtin_amdgcn_mfma_f32_16x16x32_bf16(
                bf[ni], af[mi], acc[mi][ni], 0, 0, 0);
      } else {
#pragma unroll
        for (int mi = 0; mi < 4; ++mi)
#pragma unroll
          for (int ni = 0; ni < 4; ++ni)
            acc[mi][ni] = __builtin_amdgcn_mfma_f32_16x16x32_bf16(
                af[mi], bf[ni], acc[mi][ni], 0, 0, 0);
      }
    }
    __syncthreads();   // all reads of cur done + own prefetch drained
    cur ^= 1;
  }

  const int bb = m0 >> 11;        // batch (block-uniform, 128 | 2048)
  const int lbase = m0 & 2047;    // seq position base within batch
  const int h0n = n0 & 1023;      // n base within the 1024-wide projection
  unsigned short* T = &Sh[0][0][0];  // 32KB transpose buffer (buf0 region)

  if (tsel < 2) {
    const float* bias = tsel == 0 ? bq : bk;
    unsigned short* dst01 = tsel == 0 ? qo : ko;
#pragma unroll
    for (int ni = 0; ni < 4; ++ni) {
      const int nlb = wc * 64 + ni * 16 + g4 * 4;
      const f32x4 b4 = *(const f32x4*)(bias + h0n + nlb);
#pragma unroll
      for (int mi = 0; mi < 4; ++mi) {
        const int ml = wr * 64 + mi * 16 + r16;
        u16x4 pk;
#pragma unroll
        for (int i = 0; i < 4; ++i) pk[i] = f2bf(acc[mi][ni][i] + b4[i]);
        int byteoff = ml * 256 + nlb * 2;   // T[m][n], 8B write (n-contig)
        byteoff ^= (ml & 7) << 4;
        *(u16x4*)((char*)T + byteoff) = pk;
      }
    }
    __syncthreads();
#pragma unroll
    for (int p = 0; p < 8; ++p) {
      const int ml = p * 16 + (t >> 4);
      int byteoff = ml * 256 + ((t & 15) << 4);
      byteoff ^= (ml & 7) << 4;
      short8 row = *(const short8*)((const char*)T + byteoff);
      const int nd = h0n + (t & 15) * 8;    // 8 consecutive n (one head)
      const int h = nd >> 6, hs = nd & 63;
      *(short8*)(dst01 + ((long)(bb * NHEAD + h) * SEQ + lbase + ml) * 64 + hs) = row;
    }
  } else {
#pragma unroll
    for (int ni = 0; ni < 4; ++ni) {
      const int nl = wc * 64 + ni * 16 + r16;
      const float bval = bv[h0n + nl];
#pragma unroll
      for (int mi = 0; mi < 4; ++mi) {
        const int mlb = wr * 64 + mi * 16 + g4 * 4;
        u16x4 pk;
#pragma unroll
        for (int i = 0; i < 4; ++i) pk[i] = f2bf(acc[mi][ni][i] + bval);
        int byteoff = nl * 256 + mlb * 2;   // T[n][m], 8B write (m-contig)
        byteoff ^= (nl & 7) << 4;
        *(u16x4*)((char*)T + byteoff) = pk;
      }
    }
    __syncthreads();
#pragma unroll
    for (int p = 0; p < 8; ++p) {
      const int nl = p * 16 + (t >> 4);
      int byteoff = nl * 256 + ((t & 15) << 4);
      byteoff ^= (nl & 7) << 4;
      short8 row = *(const short8*)((const char*)T + byteoff);
      const int nd = h0n + nl;
      const int h = nd >> 6, hs = nd & 63;
      *(short8*)(vto + ((((long)(bb * NHEAD + h)) << 6) + hs) * SEQ + lbase +
                 (t & 15) * 8) = row;
    }
  }
}

// ---------------------------------------------------------------------------
// Kernel 3: flash attention, 32x32 swapped-operand structure.
// Round-9: 1024 blocks x 2 waves (64 q-rows/block) -> 4 independent barrier
// domains per CU instead of 2; everything else identical to passing round 8.
// ---------------------------------------------------------------------------
__global__ __launch_bounds__(128, 2) void attn_kernel(
    const unsigned short* __restrict__ qb, const unsigned short* __restrict__ kb,
    const unsigned short* __restrict__ vtb, const float* __restrict__ mask,
    float* __restrict__ out) {
  // K dbuf 16KB + V dbuf 16KB; epilogue reuses first 17.4KB as OutT f32 [2][32*68]
  __shared__ __attribute__((aligned(16))) char lds[32768];
  unsigned short* Ks = (unsigned short*)lds;             // [2][64*64]
  unsigned short* Vs = (unsigned short*)(lds + 16384);   // [2][64*64]  rows = d

  const int bid = blockIdx.x;                    // 1024 blocks
  const int swz = (bid & 7) * 128 + (bid >> 3);  // XCD chunks; h fastest -> mask L2 reuse
  const int h = swz & 15, grp = swz >> 4;        // grp in [0,64)
  const int qt = grp & 31, b = grp >> 5;         // 32 q-tiles of 64 rows
  const int bh = b * NHEAD + h;

  const int t = threadIdx.x;
  const int lane = t & 63, w = t >> 6;           // w in {0,1}
  const int lq = lane & 31;      // q (QK) / d (PV) row-within-32, and C/D column
  const int hi = lane >> 5;      // half-select (k-slice of fragments)

  const unsigned short* qg = qb + (long)bh * SEQ * 64;
  const unsigned short* kg = kb + (long)bh * SEQ * 64;
  const unsigned short* vg = vtb + (long)bh * 64 * SEQ;
  const int q0 = qt * 64 + w * 32;
  const float* mrow = mask + (long)b * SEQ * SEQ + (long)(q0 + lq) * SEQ;

  // stage K/V tile kt into buffer buf: pre-swizzled global source, linear LDS
  // 2 waves x 4 ops cover the 64 rows of each tile.
  auto stageKV = [&](int kt, int buf) {
#pragma unroll
    for (int r = 0; r < 4; ++r) {
      const int row = w * 32 + r * 8 + (lane >> 3);
      const int gsw = ((lane & 7) ^ (row & 7)) * 8;
      gload_lds16(kg + (long)(kt * 64 + row) * 64 + gsw,
                  (char*)Ks + buf * 8192 + w * 4096 + r * 1024);
      gload_lds16(vg + (long)row * SEQ + kt * 64 + gsw,
                  (char*)Vs + buf * 8192 + w * 4096 + r * 1024);
    }
  };

  stageKV(0, 0);

  // Q fragments: direct global->reg; lane lq holds Q[q0+lq][hi*8 + j + kk*16]
  short8 qf[4];
#pragma unroll
  for (int kk = 0; kk < 4; ++kk)
    qf[kk] = *(const short8*)(qg + (long)(q0 + lq) * 64 + hi * 8 + kk * 16);

  f32x16 oa0 = {}, oa1 = {};     // O^T acc, d-tiles 0 (d 0-31) and 1 (d 32-63)
  float m_st = -1e30f, l_st = 0.f;
  const float L2E = 1.4426950408889634f;

  __syncthreads();

  int cur = 0;
  for (int kt = 0; kt < 32; ++kt) {
    if (kt < 31) stageKV(kt + 1, cur ^ 1);   // prefetch under compute

    const char* Kb = (const char*)Ks + cur * 8192;
    const char* Vb = (const char*)Vs + cur * 8192;

    // mask: 8x float4; mv[k2][g] covers kv = kt*64 + k2*32 + g*8 + hi*4 + (0..3)
    f32x4 mv[2][4];
#pragma unroll
    for (int k2 = 0; k2 < 2; ++k2)
#pragma unroll
      for (int g = 0; g < 4; ++g)
        mv[k2][g] = *(const f32x4*)(mrow + kt * 64 + k2 * 32 + g * 8 + hi * 4);

    // S^T[kv][q] = K . Q^T : 2 kv-subtiles x 4 d-frags
    f32x16 sa0 = {}, sa1 = {};
    __builtin_amdgcn_s_setprio(1);
#pragma unroll
    for (int kk = 0; kk < 4; ++kk) {
      const int r0 = lq;
      short8 kf0 = *(const short8*)(Kb + r0 * 128 + (((hi + 2 * kk) ^ (r0 & 7)) << 4));
      sa0 = __builtin_amdgcn_mfma_f32_32x32x16_bf16(kf0, qf[kk], sa0, 0, 0, 0);
      const int r1 = 32 + lq;
      short8 kf1 = *(const short8*)(Kb + r1 * 128 + (((hi + 2 * kk) ^ (r1 & 7)) << 4));
      sa1 = __builtin_amdgcn_mfma_f32_32x32x16_bf16(kf1, qf[kk], sa1, 0, 0, 0);
    }
    __builtin_amdgcn_s_setprio(0);

    // scale + mask  (s[r]: kv_local = (r&3) + 8*(r>>2) + 4*hi (+32 for r>=16))
    float s[32];
#pragma unroll
    for (int r = 0; r < 16; ++r)
      s[r] = sa0[r] * 0.125f + mv[0][r >> 2][r & 3];
#pragma unroll
    for (int r = 0; r < 16; ++r)
      s[16 + r] = sa1[r] * 0.125f + mv[1][r >> 2][r & 3];

    // row max: 4-chain ILP tree + one cross-half shuffle
    float pm0 = s[0], pm1 = s[1], pm2 = s[2], pm3 = s[3];
#pragma unroll
    for (int r = 4; r < 32; r += 4) {
      pm0 = fmaxf(pm0, s[r]);     pm1 = fmaxf(pm1, s[r + 1]);
      pm2 = fmaxf(pm2, s[r + 2]); pm3 = fmaxf(pm3, s[r + 3]);
    }
    float pm = fmaxf(fmaxf(pm0, pm1), fmaxf(pm2, pm3));
    pm = fmaxf(pm, __shfl_xor(pm, 32, 64));

    // defer-max (T13): only rescale when the running max grew by > 8
    if (!__all(pm <= m_st + 8.0f)) {
      const float mn = fmaxf(m_st, pm);
      const float alpha = exp2f((m_st - mn) * L2E);
      m_st = mn;
      l_st *= alpha;
#pragma unroll
      for (int r = 0; r < 16; ++r) { oa0[r] *= alpha; oa1[r] *= alpha; }
    }

    // P = exp2(s*L2E - m*L2E): fma + v_exp per element; 4-chain sum
    const float nml2e = -m_st * L2E;
    float rs0 = 0.f, rs1 = 0.f, rs2 = 0.f, rs3 = 0.f;
#pragma unroll
    for (int r = 0; r < 32; r += 4) {
      const float p0 = exp2f(fmaf(s[r], L2E, nml2e));
      const float p1 = exp2f(fmaf(s[r + 1], L2E, nml2e));
      const float p2 = exp2f(fmaf(s[r + 2], L2E, nml2e));
      const float p3 = exp2f(fmaf(s[r + 3], L2E, nml2e));
      s[r] = p0; s[r + 1] = p1; s[r + 2] = p2; s[r + 3] = p3;
      rs0 += p0; rs1 += p1; rs2 += p2; rs3 += p3;
    }
    float rs = (rs0 + rs1) + (rs2 + rs3);
    rs += __shfl_xor(rs, 32, 64);
    l_st += rs;

    // P -> bf16 B-fragments. Frag kk, lane (hi,lq), word j2 must hold
    //   P[q=lq][kv = kk*16 + hi*8 + 2*j2 .. +1]
    //   word0 = hi ? partnerY  : ownX     word1 = hi ? partnerY2 : ownX2
    //   word2 = hi ? ownY      : partnerX word3 = hi ? ownY2     : partnerX2
    u32x4 pw[4];
#pragma unroll
    for (int kk = 0; kk < 4; ++kk) {
      const int base = kk * 8;
      const unsigned X  = pack2bf(s[base + 0], s[base + 1]);
      const unsigned X2 = pack2bf(s[base + 2], s[base + 3]);
      const unsigned Y  = pack2bf(s[base + 4], s[base + 5]);
      const unsigned Y2 = pack2bf(s[base + 6], s[base + 7]);
      const unsigned Xp  = __shfl_xor(X, 32, 64);
      const unsigned X2p = __shfl_xor(X2, 32, 64);
      const unsigned Yp  = __shfl_xor(Y, 32, 64);
      const unsigned Y2p = __shfl_xor(Y2, 32, 64);
      pw[kk][0] = hi ? Yp : X;
      pw[kk][1] = hi ? Y2p : X2;
      pw[kk][2] = hi ? Y : Xp;
      pw[kk][3] = hi ? Y2 : X2p;
    }

    // O^T += V^T . P^T : 2 d-tiles x 4 kv-frags
    __builtin_amdgcn_s_setprio(1);
#pragma unroll
    for (int kk = 0; kk < 4; ++kk) {
      const short8 pf = __builtin_bit_cast(short8, pw[kk]);
      const int r0 = lq;
      short8 vf0 = *(const short8*)(Vb + r0 * 128 + (((hi + 2 * kk) ^ (r0 & 7)) << 4));
      oa0 = __builtin_amdgcn_mfma_f32_32x32x16_bf16(vf0, pf, oa0, 0, 0, 0);
      const int r1 = 32 + lq;
      short8 vf1 = *(const short8*)(Vb + r1 * 128 + (((hi + 2 * kk) ^ (r1 & 7)) << 4));
      oa1 = __builtin_amdgcn_mfma_f32_32x32x16_bf16(vf1, pf, oa1, 0, 0, 0);
    }
    __builtin_amdgcn_s_setprio(0);

    __syncthreads();   // publish prefetched buffers; 1 barrier/tile (2 waves)
    cur ^= 1;
  }

  // Epilogue: O^T/l -> LDS transpose (per-wave region) -> coalesced f32 stores
  __syncthreads();     // all K/V reads done; LDS reused
  float* ot = (float*)lds + w * (32 * 68);
  const float inv_l = 1.f / l_st;
#pragma unroll
  for (int g = 0; g < 4; ++g) {
    f32x4 v0, v1;
#pragma unroll
    for (int j = 0; j < 4; ++j) { v0[j] = oa0[g * 4 + j] * inv_l;
                                  v1[j] = oa1[g * 4 + j] * inv_l; }
    *(f32x4*)(ot + lq * 68 + g * 8 + hi * 4) = v0;        // d = 8g+4hi+j
    *(f32x4*)(ot + lq * 68 + 32 + g * 8 + hi * 4) = v1;   // d = 32+8g+4hi+j
  }
  asm volatile("s_waitcnt lgkmcnt(0)" ::: "memory");
  float* ob = out + (long)b * SEQ * DMODEL + (long)q0 * DMODEL + h * 64;
#pragma unroll
  for (int j = 0; j < 8; ++j) {
    const int qr = j * 4 + (lane >> 4);
    f32x4 v4 = *(const f32x4*)(ot + qr * 68 + (lane & 15) * 4);
    *(f32x4*)(ob + (long)qr * DMODEL + (lane & 15) * 4) = v4;
  }
}

// ---------------------------------------------------------------------------
extern "C" void kernel_launch(void* const* d_in, const int* in_sizes, int n_in,
                              void* d_out, int out_size, void* d_ws, size_t ws_size,
                              hipStream_t stream) {
  const float* x    = (const float*)d_in[0];
  const float* mask = (const float*)d_in[1];
  const float* Wq   = (const float*)d_in[2];
  const float* bq   = (const float*)d_in[3];
  const float* Wk   = (const float*)d_in[4];
  const float* bk   = (const float*)d_in[5];
  const float* Wv   = (const float*)d_in[6];
  const float* bv   = (const float*)d_in[7];
  float* out = (float*)d_out;

  char* ws = (char*)d_ws;
  unsigned short* xb  = (unsigned short*)(ws);                     // 8 MB
  unsigned short* wb  = (unsigned short*)(ws + (8L << 20));        // 6 MB
  unsigned short* qo  = (unsigned short*)(ws + (14L << 20));       // 8 MB
  unsigned short* ko  = (unsigned short*)(ws + (22L << 20));       // 8 MB
  unsigned short* vto = (unsigned short*)(ws + (30L << 20));       // 8 MB  (38 MB total)

  convert_kernel<<<7168, 256, 0, stream>>>(x, Wq, Wk, Wv, xb, wb);
  qkv_gemm<<<768, 256, 0, stream>>>(xb, wb, bq, bk, bv, qo, ko, vto);
  attn_kernel<<<1024, 128, 0, stream>>>(qo, ko, vto, mask, out);
}

// Round 11
// 237.920 us; speedup vs baseline: 1.0413x; 1.0413x over previous
//
#include <hip/hip_runtime.h>
#include <cstdint>

// Problem constants: B=2, L=2048, D=1024, H=16, HS=64
#define SEQ 2048
#define DMODEL 1024
#define NHEAD 16
#define HEADSZ 64

typedef __attribute__((ext_vector_type(4))) float f32x4;
typedef __attribute__((ext_vector_type(16))) float f32x16;
typedef __attribute__((ext_vector_type(8))) short short8;
typedef __attribute__((ext_vector_type(4))) unsigned short u16x4;
typedef __attribute__((ext_vector_type(4))) unsigned int u32x4;

#define AS1 __attribute__((address_space(1)))
#define AS3 __attribute__((address_space(3)))

__device__ __forceinline__ void gload_lds16(const void* g, void* l) {
  // async global->LDS, 16B per lane; LDS dest is wave-uniform base (+lane*16 by HW)
  __builtin_amdgcn_global_load_lds((const AS1 void*)g, (AS3 void*)l, 16, 0, 0);
}

__device__ __forceinline__ unsigned short f2bf(float f) {
  unsigned u = __float_as_uint(f);
  u += 0x7fffu + ((u >> 16) & 1u);   // RNE
  return (unsigned short)(u >> 16);
}

__device__ __forceinline__ unsigned pack2bf(float lo, float hi) {
  return (unsigned)f2bf(lo) | ((unsigned)f2bf(hi) << 16);
}

// ---------------------------------------------------------------------------
// Kernel 1: fp32 -> bf16 conversion of x and concat(Wq,Wk,Wv)
// ---------------------------------------------------------------------------
__global__ __launch_bounds__(256) void convert_kernel(
    const float* __restrict__ x, const float* __restrict__ wq,
    const float* __restrict__ wk, const float* __restrict__ wv,
    unsigned short* __restrict__ xb, unsigned short* __restrict__ wb) {
  const long i = ((long)blockIdx.x * 256 + threadIdx.x) * 4;
  const float* src;
  unsigned short* dst;
  if (i < (1L << 22)) {               // x: 4M elements
    src = x + i; dst = xb + i;
  } else {
    const long j = i - (1L << 22);    // wb: 3M elements (Wq|Wk|Wv rows)
    dst = wb + j;
    if (j < (1L << 20))        src = wq + j;
    else if (j < (2L << 20))   src = wk + (j - (1L << 20));
    else                       src = wv + (j - (2L << 20));
  }
  f32x4 v = *(const f32x4*)src;
  u16x4 o;
  o.x = f2bf(v.x); o.y = f2bf(v.y); o.z = f2bf(v.z); o.w = f2bf(v.w);
  *(u16x4*)dst = o;
}

// ---------------------------------------------------------------------------
// Kernel 2: QKV projection GEMM.  Round-11: LDS dbuf (kept from r10) + XOR
// bank swizzle on the staged tiles (both sides: pre-swizzled global source
// column, swizzled ds_read offset). Previously reads were a 16-way conflict
// (lanes 0-15 at 128B row stride -> same bank), never fixed here.
// ---------------------------------------------------------------------------
__global__ __launch_bounds__(256) void qkv_gemm(
    const unsigned short* __restrict__ xb, const unsigned short* __restrict__ wb,
    const float* __restrict__ bq, const float* __restrict__ bk,
    const float* __restrict__ bv,
    unsigned short* __restrict__ qo, unsigned short* __restrict__ ko,
    unsigned short* __restrict__ vto) {
  __shared__ __attribute__((aligned(16))) unsigned short Sh[2][2][128 * 64]; // 64KB

  const int bid = blockIdx.x;                  // nwg = 32*24 = 768 (div by 8)
  const int swz = (bid & 7) * 96 + (bid >> 3); // XCD-contiguous chunks
  const int tm = swz / 24, tn = swz % 24;
  const int m0 = tm * 128, n0 = tn * 128;
  const int tsel = n0 >> 10;                   // block-uniform: 0=Q 1=K 2=V
  const int t = threadIdx.x;
  const int lane = t & 63, wid = t >> 6;
  const int wr = wid >> 1, wc = wid & 1;
  const int r16 = lane & 15, g4 = lane >> 4;
  const int swzr = r16 & 7;                    // read-side row swizzle key

  f32x4 acc[4][4] = {};

  // pre-swizzled source column: granule (t&7) XOR (row&7); rows step by 32 (≡0 mod 8)
  const int csel = ((t & 7) ^ ((t >> 3) & 7)) * 8;
  const unsigned short* ga0 = xb + (long)(m0 + (t >> 3)) * 1024 + csel;
  const unsigned short* gb0 = wb + (long)(n0 + (t >> 3)) * 1024 + csel;

  // stage K-step ks into buffer buf
  auto stage = [&](int ks, int buf) {
    const unsigned short* ga = ga0 + ks * 64;
    const unsigned short* gb = gb0 + ks * 64;
    char* lA = (char*)&Sh[buf][0][0] + wid * 1024;
    char* lB = (char*)&Sh[buf][1][0] + wid * 1024;
#pragma unroll
    for (int r = 0; r < 4; ++r) {
      gload_lds16(ga + r * 32 * 1024, lA + r * 4096);
      gload_lds16(gb + r * 32 * 1024, lB + r * 4096);
    }
  };

  stage(0, 0);
  __syncthreads();

  int cur = 0;
  for (int ks = 0; ks < 16; ++ks) {
    if (ks < 15) stage(ks + 1, cur ^ 1);   // loads fly under this step's MFMA
    const char* As = (const char*)&Sh[cur][0][0];
    const char* Bs = (const char*)&Sh[cur][1][0];
#pragma unroll
    for (int kk = 0; kk < 2; ++kk) {
      short8 af[4], bf[4];
#pragma unroll
      for (int mi = 0; mi < 4; ++mi)
        af[mi] = *(const short8*)(As + (wr * 64 + mi * 16 + r16) * 128 +
                 (((kk * 4 + g4) ^ swzr) << 4));
#pragma unroll
      for (int ni = 0; ni < 4; ++ni)
        bf[ni] = *(const short8*)(Bs + (wc * 64 + ni * 16 + r16) * 128 +
                 (((kk * 4 + g4) ^ swzr) << 4));
      if (tsel < 2) {
#pragma unroll
        for (int mi = 0; mi < 4; ++mi)
#pragma unroll
          for (int ni = 0; ni < 4; ++ni)
            acc[mi][ni] = __builtin_amdgcn_mfma_f32_16x16x32_bf16(
                bf[ni], af[mi], acc[mi][ni], 0, 0, 0);
      } else {
#pragma unroll
        for (int mi = 0; mi < 4; ++mi)
#pragma unroll
          for (int ni = 0; ni < 4; ++ni)
            acc[mi][ni] = __builtin_amdgcn_mfma_f32_16x16x32_bf16(
                af[mi], bf[ni], acc[mi][ni], 0, 0, 0);
      }
    }
    __syncthreads();   // all reads of cur done + own prefetch drained
    cur ^= 1;
  }

  const int bb = m0 >> 11;        // batch (block-uniform, 128 | 2048)
  const int lbase = m0 & 2047;    // seq position base within batch
  const int h0n = n0 & 1023;      // n base within the 1024-wide projection
  unsigned short* T = &Sh[0][0][0];  // 32KB transpose buffer (buf0 region)

  if (tsel < 2) {
    const float* bias = tsel == 0 ? bq : bk;
    unsigned short* dst01 = tsel == 0 ? qo : ko;
#pragma unroll
    for (int ni = 0; ni < 4; ++ni) {
      const int nlb = wc * 64 + ni * 16 + g4 * 4;
      const f32x4 b4 = *(const f32x4*)(bias + h0n + nlb);
#pragma unroll
      for (int mi = 0; mi < 4; ++mi) {
        const int ml = wr * 64 + mi * 16 + r16;
        u16x4 pk;
#pragma unroll
        for (int i = 0; i < 4; ++i) pk[i] = f2bf(acc[mi][ni][i] + b4[i]);
        int byteoff = ml * 256 + nlb * 2;   // T[m][n], 8B write (n-contig)
        byteoff ^= (ml & 7) << 4;
        *(u16x4*)((char*)T + byteoff) = pk;
      }
    }
    __syncthreads();
#pragma unroll
    for (int p = 0; p < 8; ++p) {
      const int ml = p * 16 + (t >> 4);
      int byteoff = ml * 256 + ((t & 15) << 4);
      byteoff ^= (ml & 7) << 4;
      short8 row = *(const short8*)((const char*)T + byteoff);
      const int nd = h0n + (t & 15) * 8;    // 8 consecutive n (one head)
      const int h = nd >> 6, hs = nd & 63;
      *(short8*)(dst01 + ((long)(bb * NHEAD + h) * SEQ + lbase + ml) * 64 + hs) = row;
    }
  } else {
#pragma unroll
    for (int ni = 0; ni < 4; ++ni) {
      const int nl = wc * 64 + ni * 16 + r16;
      const float bval = bv[h0n + nl];
#pragma unroll
      for (int mi = 0; mi < 4; ++mi) {
        const int mlb = wr * 64 + mi * 16 + g4 * 4;
        u16x4 pk;
#pragma unroll
        for (int i = 0; i < 4; ++i) pk[i] = f2bf(acc[mi][ni][i] + bval);
        int byteoff = nl * 256 + mlb * 2;   // T[n][m], 8B write (m-contig)
        byteoff ^= (nl & 7) << 4;
        *(u16x4*)((char*)T + byteoff) = pk;
      }
    }
    __syncthreads();
#pragma unroll
    for (int p = 0; p < 8; ++p) {
      const int nl = p * 16 + (t >> 4);
      int byteoff = nl * 256 + ((t & 15) << 4);
      byteoff ^= (nl & 7) << 4;
      short8 row = *(const short8*)((const char*)T + byteoff);
      const int nd = h0n + nl;
      const int h = nd >> 6, hs = nd & 63;
      *(short8*)(vto + ((((long)(bb * NHEAD + h)) << 6) + hs) * SEQ + lbase +
                 (t & 15) * 8) = row;
    }
  }
}

// ---------------------------------------------------------------------------
// Kernel 3: flash attention, 32x32 swapped-operand structure.
// REVERTED to round-8 config (512 blocks x 4 waves, measured 118.6us) —
// round-10's 2-wave split regressed to 128.7us (occupancy 20->16%).
// ---------------------------------------------------------------------------
__global__ __launch_bounds__(256, 2) void attn_kernel(
    const unsigned short* __restrict__ qb, const unsigned short* __restrict__ kb,
    const unsigned short* __restrict__ vtb, const float* __restrict__ mask,
    float* __restrict__ out) {
  // K dbuf 16KB + V dbuf 16KB; epilogue reuses all 34816B as OutT f32 [4][32*68]
  __shared__ __attribute__((aligned(16))) char lds[34816];
  unsigned short* Ks = (unsigned short*)lds;             // [2][64*64]
  unsigned short* Vs = (unsigned short*)(lds + 16384);   // [2][64*64]  rows = d

  const int bid = blockIdx.x;                   // 512 blocks
  const int swz = (bid & 7) * 64 + (bid >> 3);  // XCD chunks; h fastest -> mask L2 reuse
  const int h = swz & 15, grp = swz >> 4;
  const int qt = grp & 15, b = grp >> 4;
  const int bh = b * NHEAD + h;

  const int t = threadIdx.x;
  const int lane = t & 63, w = t >> 6;
  const int lq = lane & 31;      // q (QK) / d (PV) row-within-32, and C/D column
  const int hi = lane >> 5;      // half-select (k-slice of fragments)

  const unsigned short* qg = qb + (long)bh * SEQ * 64;
  const unsigned short* kg = kb + (long)bh * SEQ * 64;
  const unsigned short* vg = vtb + (long)bh * 64 * SEQ;
  const int q0 = qt * 128 + w * 32;
  const float* mrow = mask + (long)b * SEQ * SEQ + (long)(q0 + lq) * SEQ;

  // stage K/V tile kt into buffer buf: pre-swizzled global source, linear LDS
  auto stageKV = [&](int kt, int buf) {
#pragma unroll
    for (int r = 0; r < 2; ++r) {
      const int row = w * 16 + r * 8 + (lane >> 3);
      const int gsw = ((lane & 7) ^ (row & 7)) * 8;
      gload_lds16(kg + (long)(kt * 64 + row) * 64 + gsw,
                  (char*)Ks + buf * 8192 + w * 2048 + r * 1024);
      gload_lds16(vg + (long)row * SEQ + kt * 64 + gsw,
                  (char*)Vs + buf * 8192 + w * 2048 + r * 1024);
    }
  };

  stageKV(0, 0);

  // Q fragments: direct global->reg; lane lq holds Q[q0+lq][hi*8 + j + kk*16]
  short8 qf[4];
#pragma unroll
  for (int kk = 0; kk < 4; ++kk)
    qf[kk] = *(const short8*)(qg + (long)(q0 + lq) * 64 + hi * 8 + kk * 16);

  f32x16 oa0 = {}, oa1 = {};     // O^T acc, d-tiles 0 (d 0-31) and 1 (d 32-63)
  float m_st = -1e30f, l_st = 0.f;
  const float L2E = 1.4426950408889634f;

  __syncthreads();

  int cur = 0;
  for (int kt = 0; kt < 32; ++kt) {
    if (kt < 31) stageKV(kt + 1, cur ^ 1);   // prefetch under compute

    const char* Kb = (const char*)Ks + cur * 8192;
    const char* Vb = (const char*)Vs + cur * 8192;

    // mask: 8x float4; mv[k2][g] covers kv = kt*64 + k2*32 + g*8 + hi*4 + (0..3)
    f32x4 mv[2][4];
#pragma unroll
    for (int k2 = 0; k2 < 2; ++k2)
#pragma unroll
      for (int g = 0; g < 4; ++g)
        mv[k2][g] = *(const f32x4*)(mrow + kt * 64 + k2 * 32 + g * 8 + hi * 4);

    // S^T[kv][q] = K . Q^T : 2 kv-subtiles x 4 d-frags
    f32x16 sa0 = {}, sa1 = {};
    __builtin_amdgcn_s_setprio(1);
#pragma unroll
    for (int kk = 0; kk < 4; ++kk) {
      const int r0 = lq;
      short8 kf0 = *(const short8*)(Kb + r0 * 128 + (((hi + 2 * kk) ^ (r0 & 7)) << 4));
      sa0 = __builtin_amdgcn_mfma_f32_32x32x16_bf16(kf0, qf[kk], sa0, 0, 0, 0);
      const int r1 = 32 + lq;
      short8 kf1 = *(const short8*)(Kb + r1 * 128 + (((hi + 2 * kk) ^ (r1 & 7)) << 4));
      sa1 = __builtin_amdgcn_mfma_f32_32x32x16_bf16(kf1, qf[kk], sa1, 0, 0, 0);
    }
    __builtin_amdgcn_s_setprio(0);

    // scale + mask  (s[r]: kv_local = (r&3) + 8*(r>>2) + 4*hi (+32 for r>=16))
    float s[32];
#pragma unroll
    for (int r = 0; r < 16; ++r)
      s[r] = sa0[r] * 0.125f + mv[0][r >> 2][r & 3];
#pragma unroll
    for (int r = 0; r < 16; ++r)
      s[16 + r] = sa1[r] * 0.125f + mv[1][r >> 2][r & 3];

    // row max: 4-chain ILP tree + one cross-half shuffle
    float pm0 = s[0], pm1 = s[1], pm2 = s[2], pm3 = s[3];
#pragma unroll
    for (int r = 4; r < 32; r += 4) {
      pm0 = fmaxf(pm0, s[r]);     pm1 = fmaxf(pm1, s[r + 1]);
      pm2 = fmaxf(pm2, s[r + 2]); pm3 = fmaxf(pm3, s[r + 3]);
    }
    float pm = fmaxf(fmaxf(pm0, pm1), fmaxf(pm2, pm3));
    pm = fmaxf(pm, __shfl_xor(pm, 32, 64));

    // defer-max (T13): only rescale when the running max grew by > 8
    if (!__all(pm <= m_st + 8.0f)) {
      const float mn = fmaxf(m_st, pm);
      const float alpha = exp2f((m_st - mn) * L2E);
      m_st = mn;
      l_st *= alpha;
#pragma unroll
      for (int r = 0; r < 16; ++r) { oa0[r] *= alpha; oa1[r] *= alpha; }
    }

    // P = exp2(s*L2E - m*L2E): fma + v_exp per element; 4-chain sum
    const float nml2e = -m_st * L2E;
    float rs0 = 0.f, rs1 = 0.f, rs2 = 0.f, rs3 = 0.f;
#pragma unroll
    for (int r = 0; r < 32; r += 4) {
      const float p0 = exp2f(fmaf(s[r], L2E, nml2e));
      const float p1 = exp2f(fmaf(s[r + 1], L2E, nml2e));
      const float p2 = exp2f(fmaf(s[r + 2], L2E, nml2e));
      const float p3 = exp2f(fmaf(s[r + 3], L2E, nml2e));
      s[r] = p0; s[r + 1] = p1; s[r + 2] = p2; s[r + 3] = p3;
      rs0 += p0; rs1 += p1; rs2 += p2; rs3 += p3;
    }
    float rs = (rs0 + rs1) + (rs2 + rs3);
    rs += __shfl_xor(rs, 32, 64);
    l_st += rs;

    // P -> bf16 B-fragments. Frag kk, lane (hi,lq), word j2 must hold
    //   P[q=lq][kv = kk*16 + hi*8 + 2*j2 .. +1]
    //   word0 = hi ? partnerY  : ownX     word1 = hi ? partnerY2 : ownX2
    //   word2 = hi ? ownY      : partnerX word3 = hi ? ownY2     : partnerX2
    u32x4 pw[4];
#pragma unroll
    for (int kk = 0; kk < 4; ++kk) {
      const int base = kk * 8;
      const unsigned X  = pack2bf(s[base + 0], s[base + 1]);
      const unsigned X2 = pack2bf(s[base + 2], s[base + 3]);
      const unsigned Y  = pack2bf(s[base + 4], s[base + 5]);
      const unsigned Y2 = pack2bf(s[base + 6], s[base + 7]);
      const unsigned Xp  = __shfl_xor(X, 32, 64);
      const unsigned X2p = __shfl_xor(X2, 32, 64);
      const unsigned Yp  = __shfl_xor(Y, 32, 64);
      const unsigned Y2p = __shfl_xor(Y2, 32, 64);
      pw[kk][0] = hi ? Yp : X;
      pw[kk][1] = hi ? Y2p : X2;
      pw[kk][2] = hi ? Y : Xp;
      pw[kk][3] = hi ? Y2 : X2p;
    }

    // O^T += V^T . P^T : 2 d-tiles x 4 kv-frags
    __builtin_amdgcn_s_setprio(1);
#pragma unroll
    for (int kk = 0; kk < 4; ++kk) {
      const short8 pf = __builtin_bit_cast(short8, pw[kk]);
      const int r0 = lq;
      short8 vf0 = *(const short8*)(Vb + r0 * 128 + (((hi + 2 * kk) ^ (r0 & 7)) << 4));
      oa0 = __builtin_amdgcn_mfma_f32_32x32x16_bf16(vf0, pf, oa0, 0, 0, 0);
      const int r1 = 32 + lq;
      short8 vf1 = *(const short8*)(Vb + r1 * 128 + (((hi + 2 * kk) ^ (r1 & 7)) << 4));
      oa1 = __builtin_amdgcn_mfma_f32_32x32x16_bf16(vf1, pf, oa1, 0, 0, 0);
    }
    __builtin_amdgcn_s_setprio(0);

    __syncthreads();   // publish prefetched buffers; 1 barrier/tile
    cur ^= 1;
  }

  // Epilogue: O^T/l -> LDS transpose (per-wave region) -> coalesced f32 stores
  __syncthreads();     // all K/V reads done; LDS reused
  float* ot = (float*)lds + w * (32 * 68);
  const float inv_l = 1.f / l_st;
#pragma unroll
  for (int g = 0; g < 4; ++g) {
    f32x4 v0, v1;
#pragma unroll
    for (int j = 0; j < 4; ++j) { v0[j] = oa0[g * 4 + j] * inv_l;
                                  v1[j] = oa1[g * 4 + j] * inv_l; }
    *(f32x4*)(ot + lq * 68 + g * 8 + hi * 4) = v0;        // d = 8g+4hi+j
    *(f32x4*)(ot + lq * 68 + 32 + g * 8 + hi * 4) = v1;   // d = 32+8g+4hi+j
  }
  asm volatile("s_waitcnt lgkmcnt(0)" ::: "memory");
  float* ob = out + (long)b * SEQ * DMODEL + (long)q0 * DMODEL + h * 64;
#pragma unroll
  for (int j = 0; j < 8; ++j) {
    const int qr = j * 4 + (lane >> 4);
    f32x4 v4 = *(const f32x4*)(ot + qr * 68 + (lane & 15) * 4);
    *(f32x4*)(ob + (long)qr * DMODEL + (lane & 15) * 4) = v4;
  }
}

// ---------------------------------------------------------------------------
extern "C" void kernel_launch(void* const* d_in, const int* in_sizes, int n_in,
                              void* d_out, int out_size, void* d_ws, size_t ws_size,
                              hipStream_t stream) {
  const float* x    = (const float*)d_in[0];
  const float* mask = (const float*)d_in[1];
  const float* Wq   = (const float*)d_in[2];
  const float* bq   = (const float*)d_in[3];
  const float* Wk   = (const float*)d_in[4];
  const float* bk   = (const float*)d_in[5];
  const float* Wv   = (const float*)d_in[6];
  const float* bv   = (const float*)d_in[7];
  float* out = (float*)d_out;

  char* ws = (char*)d_ws;
  unsigned short* xb  = (unsigned short*)(ws);                     // 8 MB
  unsigned short* wb  = (unsigned short*)(ws + (8L << 20));        // 6 MB
  unsigned short* qo  = (unsigned short*)(ws + (14L << 20));       // 8 MB
  unsigned short* ko  = (unsigned short*)(ws + (22L << 20));       // 8 MB
  unsigned short* vto = (unsigned short*)(ws + (30L << 20));       // 8 MB  (38 MB total)

  convert_kernel<<<7168, 256, 0, stream>>>(x, Wq, Wk, Wv, xb, wb);
  qkv_gemm<<<768, 256, 0, stream>>>(xb, wb, bq, bk, bv, qo, ko, vto);
  attn_kernel<<<512, 256, 0, stream>>>(qo, ko, vto, mask, out);
}